// Round 7
// baseline (153.210 us; speedup 1.0000x reference)
//
#include <hip/hip_runtime.h>
#include <hip/hip_bf16.h>
#include <math.h>

// DCNv1 fused, bf16-MFMA, round 20: pos-split (NT=32), full-K acc, no reduce.
// r19 post-mortem: regression had 3 separable causes, all fixed here:
//  (1) per-thread off[] reloads (+10MB FETCH)  -> Phase-A LDS meta restored,
//      register-cached with refresh-on-tap-change (r18/r19 mistake undone).
//  (2) scalar d_out stores write-amplified 4.6x (WRITE 78MB vs 16.8 payload)
//      -> epilogue LDS-transpose + float4 stores (as reduce2 always did).
//  (3) grid 256 = 1 block/CU exposed serial gaps (1->2 matters; 2->4 doesn't,
//      r17) -> grid 512 via POS-split (wo halves), which unlike oc-split
//      duplicates zero sampling work and unlike K-split needs no reduction.
// Plus: phase = 4 chunks (barrier rate halved vs r15), acc holds full K
// (16 VGPR), WROW 40->34 (both ds_write and ds_read provably conflict-free:
// stride/4 = 17, odd -> 16 distinct banks per quarter-wave).

constexpr int B  = 4;
constexpr int C  = 256;
constexpr int H  = 64;
constexpr int W  = 64;
constexpr int OC = 256;
constexpr int Ho = 64;
constexpr int Wo = 64;

constexpr int NPOS   = 32;   // positions per block (half wo row)
constexpr int CHUNKS = 72;   // 2304 / 32
constexpr int WROW   = 34;   // padded s_col row (bf16): 68 B rows, odd/4 stride

constexpr size_t WB_ELTS  = (size_t)CHUNKS * 16 * 512;    // 589824 ushorts
constexpr size_t XB_ELTS  = (size_t)B * 8 * 4096 * 32;    // 4194304 ushorts

typedef __attribute__((ext_vector_type(8))) short bf16x8;
typedef __attribute__((ext_vector_type(4))) float f32x4;

__device__ __forceinline__ float bf_lo(unsigned u) {
    union { unsigned i; float f; } c; c.i = u << 16; return c.f;
}
__device__ __forceinline__ float bf_hi(unsigned u) {
    union { unsigned i; float f; } c; c.i = u & 0xffff0000u; return c.f;
}
__device__ __forceinline__ ushort fbf(float f) {
    __hip_bfloat16 h = __float2bfloat16(f); return *(ushort*)&h;
}

// ---- fused pre-pass: blocks 0..1023 transpose x, blocks 1024..1279 do w ----
// (x path writes 40-elt rows in its private LDS tile; unrelated to WROW=34.)
constexpr int XROW = 40;
__global__ __launch_bounds__(256)
void prep_all(const float* __restrict__ x, const float* __restrict__ wt,
              ushort* __restrict__ xb, ushort* __restrict__ wB)
{
    __shared__ ushort sx[128 * XROW];         // x path: [hw][40]
    __shared__ ushort sw[CHUNKS * XROW];      // w path: [ch][40]
    const int t = threadIdx.x;

    if (blockIdx.x < 1024) {
        // ---- x: fp32 NCHW -> bf16 [b][cb][hw][c32] ----
        const int blk = blockIdx.x;           // (b*8+cb)*32 + hwb
        const int hwb = blk & 31;
        const int cb  = (blk >> 5) & 7;
        const int b   = blk >> 8;
        const int hw0 = hwb << 7;
        const int lhw = t & 127, chalf = t >> 7;
        #pragma unroll
        for (int i = 0; i < 16; ++i) {
            const int c = i * 2 + chalf;      // 0..31
            sx[lhw * XROW + c] =
                fbf(x[(((size_t)(b * 256 + cb * 32 + c)) << 12) + hw0 + lhw]);
        }
        __syncthreads();
        const int whw = t >> 1, wh = t & 1;   // 4 uint4 per 64-B hw row
        const uint4 v0 = *(const uint4*)&sx[whw * XROW + wh * 16];
        const uint4 v1 = *(const uint4*)&sx[whw * XROW + wh * 16 + 8];
        uint4* dst = (uint4*)(xb + ((size_t)((b * 8 + cb) * 4096 + hw0) << 5));
        dst[whw * 4 + wh * 2 + 0] = v0;
        dst[whw * 4 + wh * 2 + 1] = v1;
    } else {
        // ---- w: fp32 [oc][c][tap] -> bf16 fragment-order wB ----
        // wB piece (ch, og=oc>>4): 1024 B = 64 lanes x 16 B; lane l = kq*16+mr
        // holds {oc = og*16+mr, k = kq*8..kq*8+7 of chunk ch}.
        const int oc = blockIdx.x - 1024;
        const int c  = t, chb = c >> 5, kk = c & 31;
        const float* wp = wt + ((size_t)oc * C + c) * 9;
        #pragma unroll
        for (int tap = 0; tap < 9; ++tap)
            sw[(tap * 8 + chb) * XROW + kk] = fbf(wp[tap]);
        __syncthreads();
        const int og = oc >> 4, mr = oc & 15;
        for (int i = t; i < CHUNKS * 4; i += 256) {
            const int ch = i >> 2, kq = i & 3;
            *(uint4*)(wB + ((size_t)ch * 16 + og) * 512 + (kq * 16 + mr) * 8) =
                *(const uint4*)&sw[ch * XROW + kq * 8];
        }
    }
}

struct GathRegs { uint4 c00, c01, c10, c11; float4 mw; };

// ---------------- main fused kernel ----------------------------------------
__global__ __launch_bounds__(512, 4)
void dcn_mfma(const ushort* __restrict__ xb, const float* __restrict__ off,
              const ushort* __restrict__ wB, float* __restrict__ out)
{
    // 32 KB shared: loop layout = s_col[2][4][32*34] (17408 B) + meta (6912 B)
    // epilogue overlays everything as float scratch (32 KB).
    __shared__ __align__(16) ushort s_mem[16384];
    ushort (*s_col)[4][NPOS * WROW] = (ushort (*)[4][NPOS * WROW])s_mem;
    int2*   s_midx = (int2*)  (s_mem + 8704);   // 288 entries, byte 17408
    float4* s_mw   = (float4*)(s_mem + 9856);   // 288 entries, byte 19712

    // grid 512: xcd = blk&7 -> (b, ho-high); inner -> (wo half, ho-low).
    // Both wo-halves of a (b,ho) row are consecutive -> same XCD (share all
    // gather corner lines in that L2).
    const int xcd    = blockIdx.x & 7;
    const int inner  = blockIdx.x >> 3;         // 0..63
    const int b      = xcd & 3;
    const int wohalf = inner & 1;
    const int ho     = ((xcd >> 2) << 5) + (inner >> 1);
    const int wo0    = wohalf << 5;
    const int tid    = threadIdx.x;

    // ---- Phase A: bilinear meta per (tap, sn); zero-fold padding into wts --
    if (tid < 9 * NPOS) {
        const int tap = tid >> 5, sn = tid & 31;
        const float dy = off[((size_t)(b * 18 + 2 * tap)     * Ho + ho) * Wo + wo0 + sn];
        const float dx = off[((size_t)(b * 18 + 2 * tap + 1) * Ho + ho) * Wo + wo0 + sn];
        const float ph = (float)(ho - 1 + tap / 3) + dy;
        const float pw = (float)(wo0 + sn - 1 + tap % 3) + dx;
        const float h0f = floorf(ph), w0f = floorf(pw);
        const int h0 = (int)h0f, w0 = (int)w0f;
        const float lh = ph - h0f, lw = pw - w0f;
        const int wb = min(max(w0, 0), W - 2);      // pair base stays in-plane
        const int ht = min(max(h0, 0), H - 1);
        const int hb = min(max(h0 + 1, 0), H - 1);
        const float s0 = (wb == w0) ? (1.f - lw) : ((wb == w0 + 1) ? lw : 0.f);
        const float s1 = (wb + 1 == w0 + 1) ? lw : ((wb + 1 == w0) ? (1.f - lw) : 0.f);
        const float wtp = (h0 >= 0 && h0 < H)         ? (1.f - lh) : 0.f;
        const float wbt = (h0 + 1 >= 0 && h0 + 1 < H) ? lh         : 0.f;
        s_midx[tid] = make_int2(ht * W + wb, hb * W + wb);
        s_mw[tid]   = make_float4(wtp * s0, wtp * s1, wbt * s0, wbt * s1);
    }

    const int lane = tid & 63;
    const int wv   = tid >> 6;        // 0..7 : oc-group of 32
    const int kq   = lane >> 4;
    const int mr   = lane & 15;

    // sampling task map: 512 tasks = 4 chunks x 32 pos x 4 sgg per phase.
    const int kc_t = tid >> 7;        // which of the phase's 4 chunks (wave-uniform)
    const int st   = tid & 127;
    const int sn   = st >> 2;         // position 0..31
    const int sgg  = st & 3;          // channel octet (4 lanes = one 64B row)
    const ushort* xb_sg = xb + ((size_t)b << 20) + (sgg << 3);

    f32x4 acc[2][2];                  // [mt 16-oc][nt 16-pos], full K
    #pragma unroll
    for (int mt = 0; mt < 2; ++mt)
        #pragma unroll
        for (int nt = 0; nt < 2; ++nt)
            acc[mt][nt] = (f32x4){0.f, 0.f, 0.f, 0.f};

    // ---- per-thread meta registers, refreshed from LDS on tap change ------
    int    ctap = -1;
    int2   mi;
    float4 mwv;
    auto refresh = [&](int p) {       // wave-uniform branch (kc_t wave-uniform)
        const int tap = (4 * p + kc_t) >> 3;
        if (tap != ctap) {
            ctap = tap;
            mi  = s_midx[tap * NPOS + sn];
            mwv = s_mw  [tap * NPOS + sn];
        }
    };

    auto issueg = [&](int p, GathRegs& g) {        // issue 4 corner gathers
        const int cb = (4 * p + kc_t) & 7;
        g.mw = mwv;
        const ushort* xp = xb_sg + ((size_t)cb << 17);
        g.c00 = *(const uint4*)(xp + ((size_t)mi.x << 5));
        g.c01 = *(const uint4*)(xp + (((size_t)mi.x + 1) << 5));
        g.c10 = *(const uint4*)(xp + ((size_t)mi.y << 5));
        g.c11 = *(const uint4*)(xp + (((size_t)mi.y + 1) << 5));
    };
    auto sampfma = [&](const GathRegs& g, int buf) {
        union { ushort pk[8]; uint4 v; } u;
        const unsigned a00[4] = {g.c00.x, g.c00.y, g.c00.z, g.c00.w};
        const unsigned a01[4] = {g.c01.x, g.c01.y, g.c01.z, g.c01.w};
        const unsigned a10[4] = {g.c10.x, g.c10.y, g.c10.z, g.c10.w};
        const unsigned a11[4] = {g.c11.x, g.c11.y, g.c11.z, g.c11.w};
        #pragma unroll
        for (int j = 0; j < 4; ++j) {
            const float vlo = g.mw.x * bf_lo(a00[j]) + g.mw.y * bf_lo(a01[j])
                            + g.mw.z * bf_lo(a10[j]) + g.mw.w * bf_lo(a11[j]);
            const float vhi = g.mw.x * bf_hi(a00[j]) + g.mw.y * bf_hi(a01[j])
                            + g.mw.z * bf_hi(a10[j]) + g.mw.w * bf_hi(a11[j]);
            u.pk[2 * j]     = fbf(vlo);
            u.pk[2 * j + 1] = fbf(vhi);
        }
        *(uint4*)&s_col[buf][kc_t][sn * WROW + sgg * 8] = u.v;
    };
    // one phase = sample 4 chunks -> barrier -> 16 MFMAs (K=128)
    auto phase = [&](int p, const GathRegs& gcur, int buf) {
        // A-frags first: L2 latency hides under sampfma's VALU work.
        bf16x8 wf[4][2];
        #pragma unroll
        for (int kc = 0; kc < 4; ++kc)
            #pragma unroll
            for (int mt = 0; mt < 2; ++mt)
                wf[kc][mt] = *(const bf16x8*)
                    (wB + ((size_t)(4 * p + kc) * 16 + wv * 2 + mt) * 512 + lane * 8);
        sampfma(gcur, buf);
        asm volatile("s_waitcnt lgkmcnt(0)" ::: "memory");  // ds_write visible
        __builtin_amdgcn_s_barrier();
        __builtin_amdgcn_sched_barrier(0);
        __builtin_amdgcn_s_setprio(1);
        #pragma unroll
        for (int kc = 0; kc < 4; ++kc)
            #pragma unroll
            for (int nt = 0; nt < 2; ++nt) {
                const bf16x8 bfr = *(const bf16x8*)
                    &s_col[buf][kc][(nt * 16 + mr) * WROW + kq * 8];
                #pragma unroll
                for (int mt = 0; mt < 2; ++mt)
                    acc[mt][nt] = __builtin_amdgcn_mfma_f32_16x16x32_bf16(
                        wf[kc][mt], bfr, acc[mt][nt], 0, 0, 0);
            }
        __builtin_amdgcn_s_setprio(0);
    };

    __syncthreads();                  // Phase-A meta visible

    GathRegs gA, gB;
    refresh(0);
    issueg(0, gA);

    #pragma unroll 1
    for (int it = 0; it < 9; ++it) {  // 18 phases = 72 chunks
        refresh(2 * it + 1);
        issueg(2 * it + 1, gB);
        phase(2 * it, gA, 0);
        if (it < 8) {
            refresh(2 * it + 2);
            issueg(2 * it + 2, gA);
        }
        phase(2 * it + 1, gB, 1);
    }

    // ---- epilogue: per-wave LDS transpose -> float4 d_out stores ----------
    __syncthreads();                  // all loop LDS reads done before overlay
    float* mysf = (float*)s_mem + wv * 1024;   // 4 KB per wave (32 oc x 32 wo)
    #pragma unroll
    for (int mt = 0; mt < 2; ++mt)
        #pragma unroll
        for (int nt = 0; nt < 2; ++nt)
            #pragma unroll
            for (int r = 0; r < 4; ++r)
                mysf[(mt * 16 + kq * 4 + r) * 32 + nt * 16 + mr] = acc[mt][nt][r];
    #pragma unroll
    for (int j = 0; j < 4; ++j) {
        const int idx = j * 64 + lane;
        const int row = idx >> 3, q = idx & 7;
        const float4 v = *(const float4*)&mysf[row * 32 + q * 4];
        const int oc = wv * 32 + row;
        *(float4*)&out[(((size_t)(b * OC + oc) * Ho + ho) << 6) + wo0 + q * 4] = v;
    }
}

extern "C" void kernel_launch(void* const* d_in, const int* in_sizes, int n_in,
                              void* d_out, int out_size, void* d_ws, size_t ws_size,
                              hipStream_t stream)
{
    const float* x   = (const float*)d_in[0];
    const float* off = (const float*)d_in[1];
    const float* wt  = (const float*)d_in[2];
    float* out = (float*)d_out;

    ushort* wB = (ushort*)d_ws;                 // 1.18 MB
    ushort* xb = wB + WB_ELTS;                  // 8.39 MB

    prep_all<<<1280, 256, 0, stream>>>(x, wt, xb, wB);
    dcn_mfma<<<512, 512, 0, stream>>>(xb, off, wB, out);
}

// Round 8
// 122.222 us; speedup vs baseline: 1.2535x; 1.2535x over previous
//
#include <hip/hip_runtime.h>
#include <hip/hip_bf16.h>
#include <math.h>

// DCNv1 fused, bf16-MFMA, round 21: r15 structure + r20-validated micro-fixes.
// r20 post-mortem: pos-split doubled chunk-instances at constant ~1450cyc
// fixed cost each -> regression. But it VALIDATED: WROW=34 (conflicts 2.9M ->
// 131K), float4 epilogue (WRITE 78->20MB), LDS-meta (FETCH back to 11.8MB).
// r21 = r15 (best measured: total 113.6us, dcn ~40) + only those validated
// grafts, decomposition untouched:
//  * WROW 40->34: ds_write (17*sn+4*sgg mod 32) and ds_read (17*mr) both
//    2-way-free per quarter-wave.
//  * meta register-cached, refreshed from LDS on (wave-uniform) tap change:
//    kills 16 LDS meta reads/phase; meta SOURCE stays the coalesced Phase-A
//    pass (not per-thread off[] -- the r18/r19 mistake).
//  * wf weight-fragment loads at TOP of phase: L2 latency hides under
//    sampfma's ~50 VALU ops.

constexpr int B  = 4;
constexpr int C  = 256;
constexpr int H  = 64;
constexpr int W  = 64;
constexpr int OC = 256;
constexpr int Ho = 64;
constexpr int Wo = 64;

constexpr int NT     = 64;   // positions per block (full wo row)
constexpr int CHUNKS = 72;   // 2304 / 32
constexpr int KCH    = 36;   // chunks per block (KSPLIT=2)
constexpr int WROW   = 34;   // padded s_col row (bf16): 68 B, 17-dword stride
constexpr int XROW   = 40;   // prep_all's private LDS row pitch

constexpr size_t WB_ELTS  = (size_t)CHUNKS * 16 * 512;    // 589824 ushorts
constexpr size_t XB_ELTS  = (size_t)B * 8 * 4096 * 32;    // 4194304 ushorts
constexpr size_t OUT_ELTS = (size_t)B * OC * Ho * Wo;     // 4194304 floats

typedef __attribute__((ext_vector_type(8))) short bf16x8;
typedef __attribute__((ext_vector_type(4))) float f32x4;

__device__ __forceinline__ float bf_lo(unsigned u) {
    union { unsigned i; float f; } c; c.i = u << 16; return c.f;
}
__device__ __forceinline__ float bf_hi(unsigned u) {
    union { unsigned i; float f; } c; c.i = u & 0xffff0000u; return c.f;
}
__device__ __forceinline__ ushort fbf(float f) {
    __hip_bfloat16 h = __float2bfloat16(f); return *(ushort*)&h;
}

// ---- fused pre-pass: blocks 0..1023 transpose x, blocks 1024..1279 do w ----
__global__ __launch_bounds__(256)
void prep_all(const float* __restrict__ x, const float* __restrict__ wt,
              ushort* __restrict__ xb, ushort* __restrict__ wB)
{
    __shared__ ushort sx[128 * XROW];         // x path: [hw][40]
    __shared__ ushort sw[CHUNKS * XROW];      // w path: [ch][40]
    const int t = threadIdx.x;

    if (blockIdx.x < 1024) {
        // ---- x: fp32 NCHW -> bf16 [b][cb][hw][c32] ----
        const int blk = blockIdx.x;           // (b*8+cb)*32 + hwb
        const int hwb = blk & 31;
        const int cb  = (blk >> 5) & 7;
        const int b   = blk >> 8;
        const int hw0 = hwb << 7;
        const int lhw = t & 127, chalf = t >> 7;
        #pragma unroll
        for (int i = 0; i < 16; ++i) {
            const int c = i * 2 + chalf;      // 0..31
            sx[lhw * XROW + c] =
                fbf(x[(((size_t)(b * 256 + cb * 32 + c)) << 12) + hw0 + lhw]);
        }
        __syncthreads();
        const int whw = t >> 1, wh = t & 1;   // 4 uint4 per 64-B hw row
        const uint4 v0 = *(const uint4*)&sx[whw * XROW + wh * 16];
        const uint4 v1 = *(const uint4*)&sx[whw * XROW + wh * 16 + 8];
        uint4* dst = (uint4*)(xb + ((size_t)((b * 8 + cb) * 4096 + hw0) << 5));
        dst[whw * 4 + wh * 2 + 0] = v0;
        dst[whw * 4 + wh * 2 + 1] = v1;
    } else {
        // ---- w: fp32 [oc][c][tap] -> bf16 fragment-order wB ----
        // wB piece (ch, og=oc>>4): 1024 B = 64 lanes x 16 B; lane l = kq*16+mr
        // holds {oc = og*16+mr, k = kq*8..kq*8+7 of chunk ch}.
        const int oc = blockIdx.x - 1024;
        const int c  = t, chb = c >> 5, kk = c & 31;
        const float* wp = wt + ((size_t)oc * C + c) * 9;
        #pragma unroll
        for (int tap = 0; tap < 9; ++tap)
            sw[(tap * 8 + chb) * XROW + kk] = fbf(wp[tap]);
        __syncthreads();
        const int og = oc >> 4, mr = oc & 15;
        for (int i = t; i < CHUNKS * 4; i += 256) {
            const int ch = i >> 2, kq = i & 3;
            *(uint4*)(wB + ((size_t)ch * 16 + og) * 512 + (kq * 16 + mr) * 8) =
                *(const uint4*)&sw[ch * XROW + kq * 8];
        }
    }
}

struct GathRegs { uint4 c00, c01, c10, c11; float4 mw; };

// ---------------- main fused kernel ----------------------------------------
__global__ __launch_bounds__(512, 4)
void dcn_mfma(const ushort* __restrict__ xb, const float* __restrict__ off,
              const ushort* __restrict__ wB, float* __restrict__ po)
{
    // double-buffered col tiles: [buf][kc][pos*34 + k8*8]   (17408 B)
    __shared__ __align__(16) ushort s_col[2][2][NT * WROW];
    __shared__ __align__(16) float4 s_mw[9 * NT];            //  9216 B
    __shared__ __align__(8)  int2   s_midx[9 * NT];          //  4608 B

    // XCD swizzle: b fixed per XCD; both khalves of a (b,ho) consecutive.
    const int xcd = blockIdx.x & 7;
    const int ii  = blockIdx.x >> 3;            // 0..63
    const int b   = xcd & 3;
    const int khalf = ii & 1;
    const int ho  = ((xcd >> 2) << 5) + (ii >> 1);
    const int ch0 = khalf * KCH;
    float* outp = po + (size_t)khalf * OUT_ELTS;
    const int tid = threadIdx.x;

    // ---- Phase A: bilinear meta per (tap, n); zero-fold padding into wts ----
    for (int s = tid; s < 9 * NT; s += 512) {
        const int n   = s & 63;
        const int tap = s >> 6;
        const float dy = off[((size_t)(b * 18 + 2 * tap)     * Ho + ho) * Wo + n];
        const float dx = off[((size_t)(b * 18 + 2 * tap + 1) * Ho + ho) * Wo + n];
        const float ph = (float)(ho - 1 + tap / 3) + dy;
        const float pw = (float)(n  - 1 + tap % 3) + dx;
        const float h0f = floorf(ph), w0f = floorf(pw);
        const int h0 = (int)h0f, w0 = (int)w0f;
        const float lh = ph - h0f, lw = pw - w0f;
        const int wb = min(max(w0, 0), W - 2);      // pair base stays in-plane
        const int ht = min(max(h0, 0), H - 1);
        const int hb = min(max(h0 + 1, 0), H - 1);
        const float s0 = (wb == w0) ? (1.f - lw) : ((wb == w0 + 1) ? lw : 0.f);
        const float s1 = (wb + 1 == w0 + 1) ? lw : ((wb + 1 == w0) ? (1.f - lw) : 0.f);
        const float wtp = (h0 >= 0 && h0 < H)         ? (1.f - lh) : 0.f;
        const float wbt = (h0 + 1 >= 0 && h0 + 1 < H) ? lh         : 0.f;
        s_midx[s] = make_int2(ht * W + wb, hb * W + wb);
        s_mw[s]   = make_float4(wtp * s0, wtp * s1, wbt * s0, wbt * s1);
    }

    const int lane = tid & 63;
    const int wv   = tid >> 6;        // 0..7 : oc-group of 32
    const int kq   = lane >> 4;
    const int mr   = lane & 15;

    // sampling task map: every thread samples one (kc, sn, sgg) per phase.
    const int kc_t = tid >> 8;        // which of the phase's 2 chunks (wave-uniform)
    const int st   = tid & 255;
    const int sn   = st >> 2;         // position 0..63
    const int sgg  = st & 3;          // channel octet 0..3 (adjacent lanes
                                      //  take 4 quarters of one 64-B row)
    const ushort* xb_sg = xb + ((size_t)b << 20) + (sgg << 3);

    f32x4 acc[2][4];                  // [mt 16-oc][nt 16-pos]
    #pragma unroll
    for (int mt = 0; mt < 2; ++mt)
        #pragma unroll
        for (int nt = 0; nt < 4; ++nt)
            acc[mt][nt] = (f32x4){0.f, 0.f, 0.f, 0.f};

    // ---- meta register cache, refreshed from LDS on tap change ------------
    int    ctap = -1;
    int2   mi;
    float4 mwv;
    auto refresh = [&](int p) {       // wave-uniform branch (kc_t wave-uniform)
        const int tap = (ch0 + 2 * p + kc_t) >> 3;
        if (tap != ctap) {
            ctap = tap;
            mi  = s_midx[tap * NT + sn];
            mwv = s_mw  [tap * NT + sn];
        }
    };

    auto issueg = [&](int p, GathRegs& g) {        // issue 4 corner gathers
        const int cb = (ch0 + 2 * p + kc_t) & 7;
        g.mw = mwv;
        const ushort* xp = xb_sg + ((size_t)cb << 17);
        g.c00 = *(const uint4*)(xp + ((size_t)mi.x << 5));
        g.c01 = *(const uint4*)(xp + (((size_t)mi.x + 1) << 5));
        g.c10 = *(const uint4*)(xp + ((size_t)mi.y << 5));
        g.c11 = *(const uint4*)(xp + (((size_t)mi.y + 1) << 5));
    };
    auto sampfma = [&](const GathRegs& g, int buf) {
        union { ushort pk[8]; uint4 v; } u;
        const unsigned a00[4] = {g.c00.x, g.c00.y, g.c00.z, g.c00.w};
        const unsigned a01[4] = {g.c01.x, g.c01.y, g.c01.z, g.c01.w};
        const unsigned a10[4] = {g.c10.x, g.c10.y, g.c10.z, g.c10.w};
        const unsigned a11[4] = {g.c11.x, g.c11.y, g.c11.z, g.c11.w};
        #pragma unroll
        for (int j = 0; j < 4; ++j) {
            const float vlo = g.mw.x * bf_lo(a00[j]) + g.mw.y * bf_lo(a01[j])
                            + g.mw.z * bf_lo(a10[j]) + g.mw.w * bf_lo(a11[j]);
            const float vhi = g.mw.x * bf_hi(a00[j]) + g.mw.y * bf_hi(a01[j])
                            + g.mw.z * bf_hi(a10[j]) + g.mw.w * bf_hi(a11[j]);
            u.pk[2 * j]     = fbf(vlo);
            u.pk[2 * j + 1] = fbf(vhi);
        }
        *(uint4*)&s_col[buf][kc_t][sn * WROW + sgg * 8] = u.v;
    };
    // one phase = sample 2 chunks -> barrier -> 16 MFMAs (K=64)
    auto phase = [&](int p, const GathRegs& gcur, int buf) {
        // wf loads FIRST: L2 latency hides under sampfma's VALU work.
        bf16x8 wf[2][2];
        const int chb = ch0 + 2 * p;
        #pragma unroll
        for (int kc = 0; kc < 2; ++kc)
            #pragma unroll
            for (int mt = 0; mt < 2; ++mt)
                wf[kc][mt] = *(const bf16x8*)
                    (wB + ((size_t)(chb + kc) * 16 + wv * 2 + mt) * 512 + lane * 8);
        sampfma(gcur, buf);
        asm volatile("s_waitcnt lgkmcnt(0)" ::: "memory");  // ds_write visible
        __builtin_amdgcn_s_barrier();
        __builtin_amdgcn_sched_barrier(0);
        __builtin_amdgcn_s_setprio(1);
        #pragma unroll
        for (int kc = 0; kc < 2; ++kc)
            #pragma unroll
            for (int nt = 0; nt < 4; ++nt) {
                const bf16x8 bfr = *(const bf16x8*)
                    &s_col[buf][kc][(nt * 16 + mr) * WROW + kq * 8];
                #pragma unroll
                for (int mt = 0; mt < 2; ++mt)
                    acc[mt][nt] = __builtin_amdgcn_mfma_f32_16x16x32_bf16(
                        wf[kc][mt], bfr, acc[mt][nt], 0, 0, 0);
            }
        __builtin_amdgcn_s_setprio(0);
    };

    __syncthreads();                  // meta visible (only full drain)

    GathRegs gA, gB;
    refresh(0);
    issueg(0, gA);                    // prologue prefetch

    #pragma unroll 1
    for (int it = 0; it < 9; ++it) {  // 18 phases = 36 chunks
        refresh(2 * it + 1);
        issueg(2 * it + 1, gB);
        phase(2 * it, gA, 0);
        if (it < 8) {
            refresh(2 * it + 2);
            issueg(2 * it + 2, gA);
        }
        phase(2 * it + 1, gB, 1);
    }

    // ---- partial write: C/D layout col = lane&15 (pos), row = kq*4 + r ----
    #pragma unroll
    for (int mt = 0; mt < 2; ++mt)
        #pragma unroll
        for (int nt = 0; nt < 4; ++nt)
            #pragma unroll
            for (int r = 0; r < 4; ++r) {
                const int oc = wv * 32 + mt * 16 + kq * 4 + r;
                const int wo = nt * 16 + mr;
                outp[((size_t)(b * OC + oc) * Ho + ho) * Wo + wo] = acc[mt][nt][r];
            }
}

// ---- reduce: out = p0 + p1 (float4) ---------------------------------------
__global__ __launch_bounds__(256)
void reduce2(const float4* __restrict__ p0, const float4* __restrict__ p1,
             float4* __restrict__ out)
{
    const int i = blockIdx.x * 256 + threadIdx.x;   // over OUT_ELTS/4
    const float4 a = p0[i], b = p1[i];
    out[i] = make_float4(a.x + b.x, a.y + b.y, a.z + b.z, a.w + b.w);
}

extern "C" void kernel_launch(void* const* d_in, const int* in_sizes, int n_in,
                              void* d_out, int out_size, void* d_ws, size_t ws_size,
                              hipStream_t stream)
{
    const float* x   = (const float*)d_in[0];
    const float* off = (const float*)d_in[1];
    const float* wt  = (const float*)d_in[2];
    float* out = (float*)d_out;

    ushort* wB = (ushort*)d_ws;                 // 1.18 MB
    ushort* xb = wB + WB_ELTS;                  // 8.39 MB
    float*  po = (float*)(xb + XB_ELTS);        // 2 x 16.78 MB partials

    prep_all<<<1280, 256, 0, stream>>>(x, wt, xb, wB);
    dcn_mfma<<<512, 512, 0, stream>>>(xb, off, wB, po);
    reduce2<<<(int)(OUT_ELTS / 4 / 256), 256, 0, stream>>>(
        (const float4*)po, (const float4*)(po + OUT_ELTS), (float4*)out);
}

// Round 9
// 119.253 us; speedup vs baseline: 1.2847x; 1.0249x over previous
//
#include <hip/hip_runtime.h>
#include <hip/hip_bf16.h>
#include <math.h>

// DCNv1 fused, bf16-MFMA, round 22: revert WROW to 40, strip setprio.
// r21 post-mortem: WROW=34 DOUBLED bank conflicts (2.95M -> 5.3M): 17-dword
// row stride gives bank-quad-MISALIGNED b128 accesses (start bank !== 0 mod 4)
// that split across quads and serialize; 40 (20 dwords, quad-aligned) is the
// better geometry. Conflict delta (~9.2k cyc/CU ~= 3.8us) == the regression.
// r22 = r21 with:
//  * WROW 34 -> 40 (revert the proven regression cause)
//  * s_setprio pair REMOVED: m190 measured setprio hurting lockstep
//    barrier-synced structures (ours: 8-wave lockstep blocks) - prio-boosted
//    MFMA waves starve the co-resident block's sampling issue.
// Kept (mechanism-sound, not implicated): meta register-cache refreshed from
// LDS on tap change; wf loads at phase top; manual lgkmcnt(0)+s_barrier
// (NOT __syncthreads - that would drain vmcnt and kill gather prefetch).

constexpr int B  = 4;
constexpr int C  = 256;
constexpr int H  = 64;
constexpr int W  = 64;
constexpr int OC = 256;
constexpr int Ho = 64;
constexpr int Wo = 64;

constexpr int NT     = 64;   // positions per block (full wo row)
constexpr int CHUNKS = 72;   // 2304 / 32
constexpr int KCH    = 36;   // chunks per block (KSPLIT=2)
constexpr int WROW   = 40;   // padded s_col row (bf16): 80 B, quad-aligned
constexpr int XROW   = 40;   // prep_all's private LDS row pitch

constexpr size_t WB_ELTS  = (size_t)CHUNKS * 16 * 512;    // 589824 ushorts
constexpr size_t XB_ELTS  = (size_t)B * 8 * 4096 * 32;    // 4194304 ushorts
constexpr size_t OUT_ELTS = (size_t)B * OC * Ho * Wo;     // 4194304 floats

typedef __attribute__((ext_vector_type(8))) short bf16x8;
typedef __attribute__((ext_vector_type(4))) float f32x4;

__device__ __forceinline__ float bf_lo(unsigned u) {
    union { unsigned i; float f; } c; c.i = u << 16; return c.f;
}
__device__ __forceinline__ float bf_hi(unsigned u) {
    union { unsigned i; float f; } c; c.i = u & 0xffff0000u; return c.f;
}
__device__ __forceinline__ ushort fbf(float f) {
    __hip_bfloat16 h = __float2bfloat16(f); return *(ushort*)&h;
}

// ---- fused pre-pass: blocks 0..1023 transpose x, blocks 1024..1279 do w ----
__global__ __launch_bounds__(256)
void prep_all(const float* __restrict__ x, const float* __restrict__ wt,
              ushort* __restrict__ xb, ushort* __restrict__ wB)
{
    __shared__ ushort sx[128 * XROW];         // x path: [hw][40]
    __shared__ ushort sw[CHUNKS * XROW];      // w path: [ch][40]
    const int t = threadIdx.x;

    if (blockIdx.x < 1024) {
        // ---- x: fp32 NCHW -> bf16 [b][cb][hw][c32] ----
        const int blk = blockIdx.x;           // (b*8+cb)*32 + hwb
        const int hwb = blk & 31;
        const int cb  = (blk >> 5) & 7;
        const int b   = blk >> 8;
        const int hw0 = hwb << 7;
        const int lhw = t & 127, chalf = t >> 7;
        #pragma unroll
        for (int i = 0; i < 16; ++i) {
            const int c = i * 2 + chalf;      // 0..31
            sx[lhw * XROW + c] =
                fbf(x[(((size_t)(b * 256 + cb * 32 + c)) << 12) + hw0 + lhw]);
        }
        __syncthreads();
        const int whw = t >> 1, wh = t & 1;   // 4 uint4 per 64-B hw row
        const uint4 v0 = *(const uint4*)&sx[whw * XROW + wh * 16];
        const uint4 v1 = *(const uint4*)&sx[whw * XROW + wh * 16 + 8];
        uint4* dst = (uint4*)(xb + ((size_t)((b * 8 + cb) * 4096 + hw0) << 5));
        dst[whw * 4 + wh * 2 + 0] = v0;
        dst[whw * 4 + wh * 2 + 1] = v1;
    } else {
        // ---- w: fp32 [oc][c][tap] -> bf16 fragment-order wB ----
        // wB piece (ch, og=oc>>4): 1024 B = 64 lanes x 16 B; lane l = kq*16+mr
        // holds {oc = og*16+mr, k = kq*8..kq*8+7 of chunk ch}.
        const int oc = blockIdx.x - 1024;
        const int c  = t, chb = c >> 5, kk = c & 31;
        const float* wp = wt + ((size_t)oc * C + c) * 9;
        #pragma unroll
        for (int tap = 0; tap < 9; ++tap)
            sw[(tap * 8 + chb) * XROW + kk] = fbf(wp[tap]);
        __syncthreads();
        const int og = oc >> 4, mr = oc & 15;
        for (int i = t; i < CHUNKS * 4; i += 256) {
            const int ch = i >> 2, kq = i & 3;
            *(uint4*)(wB + ((size_t)ch * 16 + og) * 512 + (kq * 16 + mr) * 8) =
                *(const uint4*)&sw[ch * XROW + kq * 8];
        }
    }
}

struct GathRegs { uint4 c00, c01, c10, c11; float4 mw; };

// ---------------- main fused kernel ----------------------------------------
__global__ __launch_bounds__(512, 4)
void dcn_mfma(const ushort* __restrict__ xb, const float* __restrict__ off,
              const ushort* __restrict__ wB, float* __restrict__ po)
{
    // double-buffered col tiles: [buf][kc][pos*40 + k8*8]   (20480 B)
    __shared__ __align__(16) ushort s_col[2][2][NT * WROW];
    __shared__ __align__(16) float4 s_mw[9 * NT];            //  9216 B
    __shared__ __align__(8)  int2   s_midx[9 * NT];          //  4608 B

    // XCD swizzle: b fixed per XCD; both khalves of a (b,ho) consecutive.
    const int xcd = blockIdx.x & 7;
    const int ii  = blockIdx.x >> 3;            // 0..63
    const int b   = xcd & 3;
    const int khalf = ii & 1;
    const int ho  = ((xcd >> 2) << 5) + (ii >> 1);
    const int ch0 = khalf * KCH;
    float* outp = po + (size_t)khalf * OUT_ELTS;
    const int tid = threadIdx.x;

    // ---- Phase A: bilinear meta per (tap, n); zero-fold padding into wts ----
    for (int s = tid; s < 9 * NT; s += 512) {
        const int n   = s & 63;
        const int tap = s >> 6;
        const float dy = off[((size_t)(b * 18 + 2 * tap)     * Ho + ho) * Wo + n];
        const float dx = off[((size_t)(b * 18 + 2 * tap + 1) * Ho + ho) * Wo + n];
        const float ph = (float)(ho - 1 + tap / 3) + dy;
        const float pw = (float)(n  - 1 + tap % 3) + dx;
        const float h0f = floorf(ph), w0f = floorf(pw);
        const int h0 = (int)h0f, w0 = (int)w0f;
        const float lh = ph - h0f, lw = pw - w0f;
        const int wb = min(max(w0, 0), W - 2);      // pair base stays in-plane
        const int ht = min(max(h0, 0), H - 1);
        const int hb = min(max(h0 + 1, 0), H - 1);
        const float s0 = (wb == w0) ? (1.f - lw) : ((wb == w0 + 1) ? lw : 0.f);
        const float s1 = (wb + 1 == w0 + 1) ? lw : ((wb + 1 == w0) ? (1.f - lw) : 0.f);
        const float wtp = (h0 >= 0 && h0 < H)         ? (1.f - lh) : 0.f;
        const float wbt = (h0 + 1 >= 0 && h0 + 1 < H) ? lh         : 0.f;
        s_midx[s] = make_int2(ht * W + wb, hb * W + wb);
        s_mw[s]   = make_float4(wtp * s0, wtp * s1, wbt * s0, wbt * s1);
    }

    const int lane = tid & 63;
    const int wv   = tid >> 6;        // 0..7 : oc-group of 32
    const int kq   = lane >> 4;
    const int mr   = lane & 15;

    // sampling task map: every thread samples one (kc, sn, sgg) per phase.
    const int kc_t = tid >> 8;        // which of the phase's 2 chunks (wave-uniform)
    const int st   = tid & 255;
    const int sn   = st >> 2;         // position 0..63
    const int sgg  = st & 3;          // channel octet 0..3 (adjacent lanes
                                      //  take 4 quarters of one 64-B row)
    const ushort* xb_sg = xb + ((size_t)b << 20) + (sgg << 3);

    f32x4 acc[2][4];                  // [mt 16-oc][nt 16-pos]
    #pragma unroll
    for (int mt = 0; mt < 2; ++mt)
        #pragma unroll
        for (int nt = 0; nt < 4; ++nt)
            acc[mt][nt] = (f32x4){0.f, 0.f, 0.f, 0.f};

    // ---- meta register cache, refreshed from LDS on tap change ------------
    int    ctap = -1;
    int2   mi;
    float4 mwv;
    auto refresh = [&](int p) {       // wave-uniform branch (kc_t wave-uniform)
        const int tap = (ch0 + 2 * p + kc_t) >> 3;
        if (tap != ctap) {
            ctap = tap;
            mi  = s_midx[tap * NT + sn];
            mwv = s_mw  [tap * NT + sn];
        }
    };

    auto issueg = [&](int p, GathRegs& g) {        // issue 4 corner gathers
        const int cb = (ch0 + 2 * p + kc_t) & 7;
        g.mw = mwv;
        const ushort* xp = xb_sg + ((size_t)cb << 17);
        g.c00 = *(const uint4*)(xp + ((size_t)mi.x << 5));
        g.c01 = *(const uint4*)(xp + (((size_t)mi.x + 1) << 5));
        g.c10 = *(const uint4*)(xp + ((size_t)mi.y << 5));
        g.c11 = *(const uint4*)(xp + (((size_t)mi.y + 1) << 5));
    };
    auto sampfma = [&](const GathRegs& g, int buf) {
        union { ushort pk[8]; uint4 v; } u;
        const unsigned a00[4] = {g.c00.x, g.c00.y, g.c00.z, g.c00.w};
        const unsigned a01[4] = {g.c01.x, g.c01.y, g.c01.z, g.c01.w};
        const unsigned a10[4] = {g.c10.x, g.c10.y, g.c10.z, g.c10.w};
        const unsigned a11[4] = {g.c11.x, g.c11.y, g.c11.z, g.c11.w};
        #pragma unroll
        for (int j = 0; j < 4; ++j) {
            const float vlo = g.mw.x * bf_lo(a00[j]) + g.mw.y * bf_lo(a01[j])
                            + g.mw.z * bf_lo(a10[j]) + g.mw.w * bf_lo(a11[j]);
            const float vhi = g.mw.x * bf_hi(a00[j]) + g.mw.y * bf_hi(a01[j])
                            + g.mw.z * bf_hi(a10[j]) + g.mw.w * bf_hi(a11[j]);
            u.pk[2 * j]     = fbf(vlo);
            u.pk[2 * j + 1] = fbf(vhi);
        }
        *(uint4*)&s_col[buf][kc_t][sn * WROW + sgg * 8] = u.v;
    };
    // one phase = sample 2 chunks -> barrier -> 16 MFMAs (K=64)
    auto phase = [&](int p, const GathRegs& gcur, int buf) {
        // wf loads FIRST: L2 latency hides under sampfma's VALU work.
        bf16x8 wf[2][2];
        const int chb = ch0 + 2 * p;
        #pragma unroll
        for (int kc = 0; kc < 2; ++kc)
            #pragma unroll
            for (int mt = 0; mt < 2; ++mt)
                wf[kc][mt] = *(const bf16x8*)
                    (wB + ((size_t)(chb + kc) * 16 + wv * 2 + mt) * 512 + lane * 8);
        sampfma(gcur, buf);
        asm volatile("s_waitcnt lgkmcnt(0)" ::: "memory");  // ds_write visible
        __builtin_amdgcn_s_barrier();
        __builtin_amdgcn_sched_barrier(0);   // no read-hoisting above barrier
        #pragma unroll
        for (int kc = 0; kc < 2; ++kc)
            #pragma unroll
            for (int nt = 0; nt < 4; ++nt) {
                const bf16x8 bfr = *(const bf16x8*)
                    &s_col[buf][kc][(nt * 16 + mr) * WROW + kq * 8];
                #pragma unroll
                for (int mt = 0; mt < 2; ++mt)
                    acc[mt][nt] = __builtin_amdgcn_mfma_f32_16x16x32_bf16(
                        wf[kc][mt], bfr, acc[mt][nt], 0, 0, 0);
            }
    };

    __syncthreads();                  // meta visible (only full drain)

    GathRegs gA, gB;
    refresh(0);
    issueg(0, gA);                    // prologue prefetch

    #pragma unroll 1
    for (int it = 0; it < 9; ++it) {  // 18 phases = 36 chunks
        refresh(2 * it + 1);
        issueg(2 * it + 1, gB);
        phase(2 * it, gA, 0);
        if (it < 8) {
            refresh(2 * it + 2);
            issueg(2 * it + 2, gA);
        }
        phase(2 * it + 1, gB, 1);
    }

    // ---- partial write: C/D layout col = lane&15 (pos), row = kq*4 + r ----
    #pragma unroll
    for (int mt = 0; mt < 2; ++mt)
        #pragma unroll
        for (int nt = 0; nt < 4; ++nt)
            #pragma unroll
            for (int r = 0; r < 4; ++r) {
                const int oc = wv * 32 + mt * 16 + kq * 4 + r;
                const int wo = nt * 16 + mr;
                outp[((size_t)(b * OC + oc) * Ho + ho) * Wo + wo] = acc[mt][nt][r];
            }
}

// ---- reduce: out = p0 + p1 (float4) ---------------------------------------
__global__ __launch_bounds__(256)
void reduce2(const float4* __restrict__ p0, const float4* __restrict__ p1,
             float4* __restrict__ out)
{
    const int i = blockIdx.x * 256 + threadIdx.x;   // over OUT_ELTS/4
    const float4 a = p0[i], b = p1[i];
    out[i] = make_float4(a.x + b.x, a.y + b.y, a.z + b.z, a.w + b.w);
}

extern "C" void kernel_launch(void* const* d_in, const int* in_sizes, int n_in,
                              void* d_out, int out_size, void* d_ws, size_t ws_size,
                              hipStream_t stream)
{
    const float* x   = (const float*)d_in[0];
    const float* off = (const float*)d_in[1];
    const float* wt  = (const float*)d_in[2];
    float* out = (float*)d_out;

    ushort* wB = (ushort*)d_ws;                 // 1.18 MB
    ushort* xb = wB + WB_ELTS;                  // 8.39 MB
    float*  po = (float*)(xb + XB_ELTS);        // 2 x 16.78 MB partials

    prep_all<<<1280, 256, 0, stream>>>(x, wt, xb, wB);
    dcn_mfma<<<512, 512, 0, stream>>>(xb, off, wB, po);
    reduce2<<<(int)(OUT_ELTS / 4 / 256), 256, 0, stream>>>(
        (const float4*)po, (const float4*)(po + OUT_ELTS), (float4*)out);
}